// Round 6
// baseline (52.913 us; speedup 1.0000x reference)
//
#include <hip/hip_runtime.h>

namespace {

constexpr int IMGSZ = 224;
constexpr int IMG2  = IMGSZ * IMGSZ;   // 50176

// ws float layout:
//   [0, 17*256*384)                  H chunk partials: ((b*17 + t)*384 + wv*192 + row*12 + ox)
//   [VOFF, VOFF+4*4*176)             pre-shifted v tables: (gi*4+sh)*176 ; vtab[i] = v[i-11-sh]
//   [UOFF, UOFF+4*128)               u tables: gi*128 + j ; utab[j] = u[j] (zero-padded)
// k = u v^T (rank-1 bicubic): u[r] = k[r][c0], v[c] = k[c0][c] / k[c0][c0].
constexpr int VOFF = 17 * 256 * 384;       // 1,671,168
constexpr int UOFF = VOFF + 4 * 4 * 176;   // +2816

__global__ __launch_bounds__(64) void prep_kernel(
    const float* __restrict__ k0, const float* __restrict__ k1,
    const float* __restrict__ k2, const float* __restrict__ k3,
    float* __restrict__ ws) {
  const int v = blockIdx.x;          // 0..15
  const int gi = v >> 2, sh = v & 3;
  const float* kp = (gi == 0) ? k0 : (gi == 1) ? k1 : (gi == 2) ? k2 : k3;
  const int KSZ = (gi == 0) ? 1 : (gi == 1) ? 12 : (gi == 2) ? 57 : 124;
  const int C0 = KSZ / 2;
  const float rpiv = 1.0f / kp[C0 * KSZ + C0];
  float* vt = ws + VOFF + v * 176;
  for (int i = threadIdx.x; i < 176; i += 64) {
    const int kk = i - 11 - sh;
    vt[i] = (kk >= 0 && kk < KSZ) ? kp[C0 * KSZ + kk] * rpiv : 0.f;
  }
  if (sh == 0) {
    float* ut = ws + UOFF + gi * 128;
    for (int j = threadIdx.x; j < 128; j += 64) {
      ut[j] = (j < KSZ) ? kp[j * KSZ + C0] : 0.f;
    }
  }
}

// One block = (b, 16-row chunk t of one glimpse). Per wave: lanes =
// (row 0..15) x (seg 0..3), global seg = wv*4+seg4. Runtime column loop
// (round-3 structure, proven; NOT unrolled), v-window read as 4 consecutive
// float4s from the L1-resident pre-shifted global table. Shfl-reduce 4 segs,
// lanes<16 store the per-wave 16x12 H partial to ws (plain stores).
// No LDS, no barriers, no atomics.
template <int G, bool CINT>
__device__ void hchunk(
    int b, int gi, int t, int ch,
    const float* __restrict__ img, const int* __restrict__ locs,
    const float* __restrict__ ws, float* __restrict__ H) {
  constexpr int KSZ  = G - 11;
  constexpr int NCB2 = (G + 2) / 4 + 1;    // aligned 4-col blocks (covers sh<=3)
  const int lane = threadIdx.x & 63;
  const int wv = threadIdx.x >> 6;
  const int r0 = ch * 16;

  const int x = locs[2 * b];
  const int y = locs[2 * b + 1];
  const int row0 = x - G / 2 + r0;
  const int col0 = y - G / 2;
  const int sh = col0 & 3;
  const int col_a0 = col0 - sh;            // image-aligned start
  const int R = (G - r0) < 16 ? (G - r0) : 16;
  const float* imgb = img + (size_t)b * (3 * IMG2);
  const float4* vt4 = reinterpret_cast<const float4*>(ws + VOFF + (gi * 4 + sh) * 176);

  const int row = lane & 15;
  const int seg = wv * 4 + (lane >> 4);    // 0..7

  float acc[12];
  #pragma unroll
  for (int i = 0; i < 12; ++i) acc[i] = 0.f;

  const int grow = row0 + row;
  if (row < R && (unsigned)grow < (unsigned)IMGSZ) {
    const float* prow = imgb + grow * IMGSZ;
    const int cend = col0 + G;
    for (int cb = seg; cb < NCB2; cb += 8) {
      const int cbase = col_a0 + 4 * cb;
      if (cbase >= cend) break;
      float sj[4];
      if (CINT) {
        // interior crop: only right image boundary needs a guard; aligned
        // blocks starting at >IMGSZ-4 are fully out-of-crop (IMGSZ%4==0).
        const bool ok = (cbase <= IMGSZ - 4);
        const int cb2 = ok ? cbase : 0;
        const float m = ok ? 1.f : 0.f;
        const float4 a  = *reinterpret_cast<const float4*>(prow + cb2);
        const float4 b4 = *reinterpret_cast<const float4*>(prow + IMG2 + cb2);
        const float4 c4 = *reinterpret_cast<const float4*>(prow + 2 * IMG2 + cb2);
        sj[0] = (a.x + b4.x + c4.x) * m;
        sj[1] = (a.y + b4.y + c4.y) * m;
        sj[2] = (a.z + b4.z + c4.z) * m;
        sj[3] = (a.w + b4.w + c4.w) * m;
      } else {
        #pragma unroll
        for (int j = 0; j < 4; ++j) {
          const int cc = cbase + j;
          const int ccl = cc < 0 ? 0 : (cc > IMGSZ - 1 ? IMGSZ - 1 : cc);
          const float s = prow[ccl] + prow[IMG2 + ccl] + prow[2 * IMG2 + ccl];
          sj[j] = ((unsigned)cc < (unsigned)IMGSZ) ? s : 0.f;
        }
      }
      float vv[16];
      {
        const float4 v0 = vt4[cb + 0];
        const float4 v1 = vt4[cb + 1];
        const float4 v2 = vt4[cb + 2];
        const float4 v3 = vt4[cb + 3];
        vv[0]=v0.x; vv[1]=v0.y; vv[2]=v0.z; vv[3]=v0.w;
        vv[4]=v1.x; vv[5]=v1.y; vv[6]=v1.z; vv[7]=v1.w;
        vv[8]=v2.x; vv[9]=v2.y; vv[10]=v2.z; vv[11]=v2.w;
        vv[12]=v3.x; vv[13]=v3.y; vv[14]=v3.z; vv[15]=v3.w;
      }
      #pragma unroll
      for (int j = 0; j < 4; ++j) {
        #pragma unroll
        for (int ox = 0; ox < 12; ++ox) {
          acc[ox] += sj[j] * vv[11 + j - ox];   // = v[c_rel - ox]
        }
      }
    }
  }

  // reduce 4 segs within the wave (segs sit at lane strides of 16)
  #pragma unroll
  for (int ox = 0; ox < 12; ++ox) {
    acc[ox] += __shfl_down(acc[ox], 32, 64);
    acc[ox] += __shfl_down(acc[ox], 16, 64);
  }
  if (lane < 16) {
    float4* dst = reinterpret_cast<float4*>(
        H + ((size_t)b * 17 + t) * 384 + wv * 192 + lane * 12);
    dst[0] = make_float4(acc[0], acc[1], acc[2], acc[3]);
    dst[1] = make_float4(acc[4], acc[5], acc[6], acc[7]);
    dst[2] = make_float4(acc[8], acc[9], acc[10], acc[11]);
  }
}

template <int G>
__device__ __forceinline__ void run_g(
    int b, int gi, int t, int ch,
    const float* __restrict__ img, const int* __restrict__ locs,
    const float* __restrict__ ws, float* __restrict__ H) {
  const int y = locs[2 * b + 1];
  const int col0 = y - G / 2;
  if (col0 >= 0 && col0 + G <= IMGSZ) {
    hchunk<G, true >(b, gi, t, ch, img, locs, ws, H);
  } else {
    hchunk<G, false>(b, gi, t, ch, img, locs, ws, H);
  }
}

__global__ __launch_bounds__(128, 6) void hpass_kernel(
    const float* __restrict__ img, const int* __restrict__ locs,
    const float* __restrict__ ws, float* __restrict__ H) {
  const int bid = blockIdx.x;
  const int b = bid & 255;
  const int t = bid >> 8;            // 0..16
  if (t == 0) {
    run_g<12 >(b, 0, t, 0,     img, locs, ws, H);
  } else if (t < 3) {
    run_g<23 >(b, 1, t, t - 1, img, locs, ws, H);
  } else if (t < 8) {
    run_g<68 >(b, 2, t, t - 3, img, locs, ws, H);
  } else {
    run_g<135>(b, 3, t, t - 8, img, locs, ws, H);
  }
}

// One block per batch image. Stage all 17 chunk partials (summing the two
// per-wave halves) + u tables into LDS; each of the 576 threads computes one
// output element: out[gi][oy][ox] = sum_ky u[ky] * H[oy+ky][ox].
__global__ __launch_bounds__(576) void vpass_kernel(
    const float* __restrict__ ws, float* __restrict__ out) {
  __shared__ __align__(16) float Hs[17 * 192];
  __shared__ float Us[512];
  const int b = blockIdx.x;
  const int tid = threadIdx.x;
  const float4* src = reinterpret_cast<const float4*>(ws + (size_t)b * 17 * 384);
  float4* Hs4 = reinterpret_cast<float4*>(Hs);
  for (int i = tid; i < 17 * 48; i += 576) {
    const int t = i / 48;
    const int j = i - t * 48;
    const float4 a = src[t * 96 + j];
    const float4 c = src[t * 96 + 48 + j];
    Hs4[t * 48 + j] = make_float4(a.x + c.x, a.y + c.y, a.z + c.z, a.w + c.w);
  }
  for (int i = tid; i < 512; i += 576) Us[i] = ws[UOFF + i];
  __syncthreads();

  const int grp = tid / 144;               // 0..3 ; heaviest taps in low waves
  const int gi = 3 - grp;
  const int e = tid - grp * 144;
  const int oy = e / 12;
  const int ox = e - oy * 12;
  const int ks = (gi == 3) ? 124 : (gi == 2) ? 57 : (gi == 1) ? 12 : 1;
  const int hb = (gi == 3) ? 1536 : (gi == 2) ? 576 : (gi == 1) ? 192 : 0;
  const float* hp = Hs + hb + oy * 12 + ox;
  const float* up = Us + gi * 128;
  float s = 0.f;
  #pragma unroll 4
  for (int ky = 0; ky < ks; ++ky) s += up[ky] * hp[ky * 12];
  out[(size_t)b * 576 + gi * 144 + e] = s;
}

}  // namespace

extern "C" void kernel_launch(void* const* d_in, const int* in_sizes, int n_in,
                              void* d_out, int out_size, void* d_ws, size_t ws_size,
                              hipStream_t stream) {
  const float* img  = (const float*)d_in[0];
  const int*   locs = (const int*)d_in[1];
  const float* k0   = (const float*)d_in[2];
  const float* k1   = (const float*)d_in[3];
  const float* k2   = (const float*)d_in[4];
  const float* k3   = (const float*)d_in[5];
  float* ws  = (float*)d_ws;
  float* out = (float*)d_out;

  prep_kernel<<<16, 64, 0, stream>>>(k0, k1, k2, k3, ws);
  hpass_kernel<<<256 * 17, 128, 0, stream>>>(img, locs, ws, ws);
  vpass_kernel<<<256, 576, 0, stream>>>(ws, out);
}

// Round 7
// 45.343 us; speedup vs baseline: 1.1670x; 1.1670x over previous
//
#include <hip/hip_runtime.h>

namespace {

constexpr int IMGSZ = 224;
constexpr int IMG2  = IMGSZ * IMGSZ;   // 50176

// One block = (b, 16-row chunk of one glimpse). 128 threads (2 waves).
// Prologue: all 128 threads cooperatively fill per-BLOCK LDS tables
//   vt[i] = v[i-11-sh] (176, zero-padded), ut[16+j] = u[j] (160, zero-padded)
// then one barrier. Main loop (per lane = (row 0..15, seg 0..3), global seg =
// wv*4+seg4): runtime column loop over image-aligned 4-col blocks (round-4
// proven structure), H[row][ox] = sum_c S[row][c]*v[c-ox] via compile-time
// register window against the LDS v-table. Shfl-reduce 4 segs per wave ->
// h_lds[wv][16][12]; barrier; 128 threads compute the vertical partial
// out[oy][ox] += sum_r u[r0+r-oy]*(h0[r][ox]+h1[r][ox]) with ONE atomicAdd
// per element. k = u v^T (rank-1): u[r]=k[r][c0], v[c]=k[c0][c]/k[c0][c0].
// Out-of-crop columns contribute 0 via the zero-padded v-table, so padded
// trailing col-blocks need only memory-safe (not exact) loads.
template <int G, bool CINT>
__device__ void chunk_glimpse(
    int b, int gi, int ch,
    const float* __restrict__ img, const int* __restrict__ locs,
    const float* __restrict__ kptr, float* __restrict__ out,
    float* __restrict__ vt, float* __restrict__ ut,
    float (*__restrict__ h_lds)[16][12]) {
  constexpr int KSZ  = G - 11;
  constexpr int C0   = KSZ / 2;
  constexpr int NCB2 = (G + 2) / 4 + 1;    // aligned 4-col blocks (covers sh<=3)
  const int tid = threadIdx.x;
  const int lane = tid & 63;
  const int wv = tid >> 6;
  const int r0 = ch * 16;

  const int x = locs[2 * b];
  const int y = locs[2 * b + 1];
  const int row0 = x - G / 2 + r0;
  const int col0 = y - G / 2;
  const int sh = col0 & 3;
  const int col_a0 = col0 - sh;            // image-aligned start
  const int R = (G - r0) < 16 ? (G - r0) : 16;
  const float* imgb = img + (size_t)b * (3 * IMG2);

  // cooperative per-block table fill (both waves share one copy)
  {
    const float rpiv = 1.0f / kptr[C0 * KSZ + C0];
    for (int i = tid; i < 176; i += 128) {
      const int kk = i - 11 - sh;
      vt[i] = (kk >= 0 && kk < KSZ) ? kptr[C0 * KSZ + kk] * rpiv : 0.f;
    }
    for (int i = tid; i < 160; i += 128) {
      const int j = i - 16;
      ut[i] = (j >= 0 && j < KSZ) ? kptr[j * KSZ + C0] : 0.f;
    }
  }
  __syncthreads();

  const int row = lane & 15;
  const int seg = wv * 4 + (lane >> 4);    // 0..7

  float acc[12];
  #pragma unroll
  for (int i = 0; i < 12; ++i) acc[i] = 0.f;

  const int grow = row0 + row;
  if (row < R && (unsigned)grow < (unsigned)IMGSZ) {
    const float* prow = imgb + grow * IMGSZ;
    const int cend = col0 + G;
    for (int cb = seg; cb < NCB2; cb += 8) {
      const int cbase = col_a0 + 4 * cb;
      if (cbase >= cend) break;
      float sj[4];
      if (CINT) {
        // interior crop: only right image boundary needs a guard; aligned
        // blocks starting at >IMGSZ-4 are fully out-of-crop (IMGSZ%4==0).
        const bool ok = (cbase <= IMGSZ - 4);
        const int cb2 = ok ? cbase : 0;
        const float m = ok ? 1.f : 0.f;
        const float4 a  = *reinterpret_cast<const float4*>(prow + cb2);
        const float4 b4 = *reinterpret_cast<const float4*>(prow + IMG2 + cb2);
        const float4 c4 = *reinterpret_cast<const float4*>(prow + 2 * IMG2 + cb2);
        sj[0] = (a.x + b4.x + c4.x) * m;
        sj[1] = (a.y + b4.y + c4.y) * m;
        sj[2] = (a.z + b4.z + c4.z) * m;
        sj[3] = (a.w + b4.w + c4.w) * m;
      } else {
        // edge: clamped-address scalar loads + select-0 (branchless)
        #pragma unroll
        for (int j = 0; j < 4; ++j) {
          const int cc = cbase + j;
          const int ccl = cc < 0 ? 0 : (cc > IMGSZ - 1 ? IMGSZ - 1 : cc);
          const float s = prow[ccl] + prow[IMG2 + ccl] + prow[2 * IMG2 + ccl];
          sj[j] = ((unsigned)cc < (unsigned)IMGSZ) ? s : 0.f;
        }
      }
      float vv[16];
      {
        const float4* vt4 = reinterpret_cast<const float4*>(vt);
        const float4 v0 = vt4[cb + 0];
        const float4 v1 = vt4[cb + 1];
        const float4 v2 = vt4[cb + 2];
        const float4 v3 = vt4[cb + 3];
        vv[0]=v0.x; vv[1]=v0.y; vv[2]=v0.z; vv[3]=v0.w;
        vv[4]=v1.x; vv[5]=v1.y; vv[6]=v1.z; vv[7]=v1.w;
        vv[8]=v2.x; vv[9]=v2.y; vv[10]=v2.z; vv[11]=v2.w;
        vv[12]=v3.x; vv[13]=v3.y; vv[14]=v3.z; vv[15]=v3.w;
      }
      #pragma unroll
      for (int j = 0; j < 4; ++j) {
        #pragma unroll
        for (int ox = 0; ox < 12; ++ox) {
          acc[ox] += sj[j] * vv[11 + j - ox];   // = v[c_rel - ox]
        }
      }
    }
  }

  // reduce 4 segs within each wave (segs sit at lane strides of 16)
  #pragma unroll
  for (int ox = 0; ox < 12; ++ox) {
    acc[ox] += __shfl_down(acc[ox], 32, 64);
    acc[ox] += __shfl_down(acc[ox], 16, 64);
  }
  if (lane < 16) {
    float4* dst = reinterpret_cast<float4*>(&h_lds[wv][lane][0]);
    dst[0] = make_float4(acc[0], acc[1], acc[2], acc[3]);
    dst[1] = make_float4(acc[4], acc[5], acc[6], acc[7]);
    dst[2] = make_float4(acc[8], acc[9], acc[10], acc[11]);
  }
  __syncthreads();

  // vertical partial over this chunk's 16 rows (both wave halves summed),
  // one atomic per output element
  float* outp = out + ((size_t)b * 4 + gi) * 144;
  for (int e = tid; e < 144; e += 128) {
    const int oy = e / 12;
    const int ox = e - oy * 12;
    float s = 0.f;
    #pragma unroll
    for (int r = 0; r < 16; ++r) {
      s += ut[16 + r0 + r - oy] * (h_lds[0][r][ox] + h_lds[1][r][ox]);
    }
    atomicAdd(&outp[e], s);
  }
}

template <int G>
__device__ __forceinline__ void run_g(
    int b, int gi, int ch,
    const float* __restrict__ img, const int* __restrict__ locs,
    const float* __restrict__ kptr, float* __restrict__ out,
    float* __restrict__ vt, float* __restrict__ ut,
    float (*__restrict__ h_lds)[16][12]) {
  const int y = locs[2 * b + 1];
  const int col0 = y - G / 2;
  if (col0 >= 0 && col0 + G <= IMGSZ) {
    chunk_glimpse<G, true >(b, gi, ch, img, locs, kptr, out, vt, ut, h_lds);
  } else {
    chunk_glimpse<G, false>(b, gi, ch, img, locs, kptr, out, vt, ut, h_lds);
  }
}

__global__ __launch_bounds__(128, 6) void glimpse_kernel(
    const float* __restrict__ img, const int* __restrict__ locs,
    const float* __restrict__ k0, const float* __restrict__ k1,
    const float* __restrict__ k2, const float* __restrict__ k3,
    float* __restrict__ out) {
  __shared__ __align__(16) float vt[176];
  __shared__ __align__(16) float ut[160];
  __shared__ __align__(16) float h_lds[2][16][12];
  const int bid = blockIdx.x;
  const int b = bid & 255;
  const int t = bid >> 8;            // 0..16 ; same-b chunks spread across XCDs
  if (t == 0) {
    run_g<12 >(b, 0, 0,     img, locs, k0, out, vt, ut, h_lds);
  } else if (t < 3) {
    run_g<23 >(b, 1, t - 1, img, locs, k1, out, vt, ut, h_lds);
  } else if (t < 8) {
    run_g<68 >(b, 2, t - 3, img, locs, k2, out, vt, ut, h_lds);
  } else {
    run_g<135>(b, 3, t - 8, img, locs, k3, out, vt, ut, h_lds);
  }
}

}  // namespace

extern "C" void kernel_launch(void* const* d_in, const int* in_sizes, int n_in,
                              void* d_out, int out_size, void* d_ws, size_t ws_size,
                              hipStream_t stream) {
  const float* img  = (const float*)d_in[0];
  const int*   locs = (const int*)d_in[1];
  const float* k0   = (const float*)d_in[2];
  const float* k1   = (const float*)d_in[3];
  const float* k2   = (const float*)d_in[4];
  const float* k3   = (const float*)d_in[5];
  float* out = (float*)d_out;

  hipMemsetAsync(out, 0, (size_t)out_size * sizeof(float), stream);
  glimpse_kernel<<<256 * 17, 128, 0, stream>>>(img, locs, k0, k1, k2, k3, out);
}